// Round 8
// baseline (2444.909 us; speedup 1.0000x reference)
//
#include <hip/hip_runtime.h>
#include <math.h>

// Problem constants: B=8, N=M=2048, D=3.
#define BB 8
#define NN 2048
#define L2E 1.4426950408889634f
#define LN2 0.6931471805599453f
#define PI_F 3.14159265358979f
#define CLIP 0.999999f
#define THSC 20860.0f            // u16 quantization scale, pi*THSC = 65533.6 < 65535
#define THSCI (1.0f / 20860.0f)

constexpr int TB   = 128;
constexpr int T16  = NN / TB;              // 16
constexpr int NXX  = T16 * (T16 + 1) / 2;  // 136
constexpr int NT   = 2 * NXX + T16 * T16;  // 528 tiles per batch
constexpr int SARR = BB * NN;              // 16384

// tile index -> (kind, I, J). kind 0: xx (I<=J), 1: yy (I<=J), 2: xy (all)
__device__ __forceinline__ void decode_tile(int bx, int& kind, int& I, int& J) {
    if (bx < NXX) kind = 0;
    else if (bx < 2 * NXX) { kind = 1; bx -= NXX; }
    else { kind = 2; bx -= 2 * NXX; }
    if (kind < 2) {
        int idx = bx; I = 0;
        for (;;) { int len = T16 - I; if (idx < len) { J = I + idx; break; } idx -= len; I++; }
    } else { I = bx >> 4; J = bx & 15; }
}

// raw acos via A&S 4.4.45 (|err| <= 7e-5 rad), input pre-clipped
__device__ __forceinline__ float acos_raw(float d) {
    const float u = fabsf(d);
    float pl = fmaf(u, -0.0187293f, 0.0742610f);
    pl = fmaf(u, pl, -0.2121144f); pl = fmaf(u, pl, 1.5707288f);
    const float rt = __builtin_amdgcn_sqrtf(1.f - u) * pl;
    return (d >= 0.f) ? rt : (PI_F - rt);
}

// theta flat offset (u16 units) — SAME formula producer & consumer.
__device__ __forceinline__ size_t th_off(int g, int wv, int lane) {
    return (size_t)(((g * 4 + wv) * 64 + lane) * 8);
}

// agent-scope (device-coherent) 8-byte store/load for cross-block partials
__device__ __forceinline__ void st_agent(float2* p, float2 v) {
    unsigned long long u; __builtin_memcpy(&u, &v, 8);
    __hip_atomic_store((unsigned long long*)p, u, __ATOMIC_RELAXED, __HIP_MEMORY_SCOPE_AGENT);
}
__device__ __forceinline__ float2 ld_agent(const float2* p) {
    unsigned long long u = __hip_atomic_load((const unsigned long long*)p,
                                             __ATOMIC_RELAXED, __HIP_MEMORY_SCOPE_AGENT);
    float2 v; __builtin_memcpy(&v, &u, 8); return v;
}

// ---------------------------------------------------------------------------
// pack: initial g = log_weights * log2(e); emit W = 2^{g-G}, per-128-block G.
// Also zeroes out[] and the fan-in counters.
// ---------------------------------------------------------------------------
__global__ __launch_bounds__(256)
void pack_kernel(const float* __restrict__ alpha, const float* __restrict__ beta,
                 float* __restrict__ gxw, float* __restrict__ gyw,
                 float* __restrict__ Wall, float* __restrict__ Gall,
                 float* __restrict__ out, unsigned int* __restrict__ cnt)
{
    const int tid = threadIdx.x;
    const int gid = blockIdx.x * 256 + tid;
    if (blockIdx.x == 0) {
        cnt[tid] = 0u; cnt[tid + 256] = 0u;
        if (tid < BB) out[tid] = 0.f;
    }
    const int o = gid >> 14, i = gid & (SARR - 1);
    const float* w = (o == 0 || o == 3) ? alpha : beta;
    const float v = w[i];
    const float g = ((v > 0.f) ? logf(fmaxf(v, 1e-30f)) : -1e5f) * L2E;
    if (o == 0) gxw[i] = g;
    if (o == 1) gyw[i] = g;
    float m = g;
    m = fmaxf(m, __shfl_xor(m, 1));  m = fmaxf(m, __shfl_xor(m, 2));
    m = fmaxf(m, __shfl_xor(m, 4));  m = fmaxf(m, __shfl_xor(m, 8));
    m = fmaxf(m, __shfl_xor(m, 16)); m = fmaxf(m, __shfl_xor(m, 32));
    __shared__ float wmax[4];
    const int wv = tid >> 6;
    if ((tid & 63) == 0) wmax[wv] = m;
    __syncthreads();
    const int grp = tid >> 7;
    const float G = fmaxf(wmax[grp * 2], wmax[grp * 2 + 1]);
    Wall[gid] = __builtin_amdgcn_exp2f(g - G);
    if ((tid & 127) == 0) Gall[gid >> 7] = G;
}

// ---------------------------------------------------------------------------
// One-time geometry pass + FUSED INIT STEP + theta write (unchanged from r7).
// ---------------------------------------------------------------------------
__global__ __launch_bounds__(256)
void maxes_kernel(const float* __restrict__ x, const float* __restrict__ y,
                  float* __restrict__ Rxx, float* __restrict__ Ryy,
                  float* __restrict__ Rxy, float* __restrict__ Cxy,
                  unsigned short* __restrict__ Theta,
                  const float* __restrict__ Wall, const float* __restrict__ Gall,
                  float2* pAX, float2* pBY, float2* pAY, float2* pBX,
                  float negK, int writeTheta)
{
    __shared__ float4 p1s[TB], p2s[TB];
    __shared__ float colred[4][TB];
    __shared__ float colpart[4][TB];
    int kind, I, J; decode_tile(blockIdx.x, kind, I, J);
    const int b = blockIdx.y, t = threadIdx.x;
    const float* P1 = (kind == 1) ? y : x;
    const float* P2 = (kind == 0) ? x : y;
    const int o1 = (kind == 0) ? 0 : (kind == 1) ? 1 : 3;
    const int o2 = (kind == 0) ? 0 : (kind == 1) ? 1 : 2;
    float2* rowOut = (kind == 0) ? pAX : (kind == 1) ? pBY : pBX;
    float2* colOut = (kind == 0) ? pAX : (kind == 1) ? pBY : pAY;
    const bool diag = (kind < 2) && (I == J);
    const float* W1 = Wall + (size_t)o1 * SARR;
    const float* W2 = Wall + (size_t)o2 * SARR;

    if (t < TB) {
        size_t gi = (size_t)b * NN + (size_t)I * TB + t;
        p1s[t] = make_float4(P1[gi * 3], P1[gi * 3 + 1], P1[gi * 3 + 2], W1[gi]);
    } else {
        int u = t - TB; size_t gi = (size_t)b * NN + (size_t)J * TB + u;
        p2s[u] = make_float4(P2[gi * 3], P2[gi * 3 + 1], P2[gi * 3 + 2], W2[gi]);
    }
    const float G1 = Gall[o1 * 128 + b * T16 + I];
    const float G2 = Gall[o2 * 128 + b * T16 + J];
    __syncthreads();
    const int lane = t & 63, wv = t >> 6, colg = lane & 7, rowg = lane >> 3;
    const int r0 = wv * 32 + rowg * 4;
    unsigned short* Tb = Theta + ((size_t)(b * NT + blockIdx.x) << 14);

    float4 pr[4];
#pragma unroll
    for (int rr = 0; rr < 4; rr++) pr[rr] = p1s[r0 + rr];
    float rmx[4] = {-2.f, -2.f, -2.f, -2.f};
    float cmx[16];
#pragma unroll
    for (int j = 0; j < 16; j++) cmx[j] = -2.f;
    float racc[4] = {0.f, 0.f, 0.f, 0.f};
    float cacc[16];
#pragma unroll
    for (int j = 0; j < 16; j++) cacc[j] = 0.f;

#pragma unroll
    for (int g = 0; g < 8; g++) {
        uint4 outv;
#pragma unroll
        for (int e = 0; e < 2; e++) {
            const int j = g * 2 + e;
            const float4 q = p2s[colg + 8 * j];
            unsigned int lo = 0, hi = 0;
#pragma unroll
            for (int rr = 0; rr < 4; rr++) {
                const float d = fmaf(pr[rr].x, q.x, fmaf(pr[rr].y, q.y, pr[rr].z * q.z));
                rmx[rr] = fmaxf(rmx[rr], d);
                cmx[j] = fmaxf(cmx[j], d);
                if (writeTheta) {
                    const float dc = fminf(fmaxf(d, -CLIP), CLIP);
                    const float th = acos_raw(dc);
                    const unsigned int qv = __float2uint_rn(th * THSC);
                    if (rr == 0) lo = qv;
                    else if (rr == 1) lo |= qv << 16;
                    else if (rr == 2) hi = qv;
                    else hi |= qv << 16;
                    const float em = __builtin_amdgcn_exp2f(th * negK);
                    racc[rr] = fmaf(q.w, em, racc[rr]);
                    cacc[j]  = fmaf(pr[rr].w, em, cacc[j]);
                }
            }
            if (e == 0) { outv.x = lo; outv.y = hi; }
            else        { outv.z = lo; outv.w = hi; }
        }
        if (writeTheta)
            *(uint4*)(Tb + th_off(g, wv, lane)) = outv;
    }

#pragma unroll
    for (int rr = 0; rr < 4; rr++) {
        float v = rmx[rr];
        v = fmaxf(v, __shfl_xor(v, 1)); v = fmaxf(v, __shfl_xor(v, 2));
        v = fmaxf(v, __shfl_xor(v, 4));
        rmx[rr] = v;
    }
    if (colg == 0) {
        float* R = (kind == 0) ? Rxx : (kind == 1) ? Ryy : Rxy;
        const size_t base = ((size_t)b * T16 + J) * NN + (size_t)I * TB + r0;
#pragma unroll
        for (int rr = 0; rr < 4; rr++)
            R[base + rr] = acos_raw(fminf(fmaxf(rmx[rr], -CLIP), CLIP));
    }
#pragma unroll
    for (int j = 0; j < 16; j++) {
        float v = cmx[j];
        v = fmaxf(v, __shfl_xor(v, 8)); v = fmaxf(v, __shfl_xor(v, 16));
        v = fmaxf(v, __shfl_xor(v, 32));
        cmx[j] = v;
    }
    if (rowg == 0) {
#pragma unroll
        for (int j = 0; j < 16; j++) colred[wv][colg + 8 * j] = cmx[j];
    }

    if (writeTheta) {
#pragma unroll
        for (int j = 0; j < 16; j++) {
            float v = cacc[j];
            v += __shfl_xor(v, 8); v += __shfl_xor(v, 16); v += __shfl_xor(v, 32);
            cacc[j] = v;
        }
        if (rowg == 0) {
#pragma unroll
            for (int j = 0; j < 16; j++) colpart[wv][colg + 8 * j] = cacc[j];
        }
#pragma unroll
        for (int rr = 0; rr < 4; rr++) {
            float v = racc[rr];
            v += __shfl_xor(v, 1); v += __shfl_xor(v, 2); v += __shfl_xor(v, 4);
            racc[rr] = v;
        }
        if (colg == 0) {
            const size_t gr = (size_t)J * SARR + (size_t)b * NN + (size_t)I * TB + r0;
#pragma unroll
            for (int rr = 0; rr < 4; rr++)
                rowOut[gr + rr] = make_float2(G2, racc[rr]);
        }
    }

    __syncthreads();
    if (t < TB) {
        const float v = fmaxf(fmaxf(colred[0][t], colred[1][t]),
                              fmaxf(colred[2][t], colred[3][t]));
        const float th = acos_raw(fminf(fmaxf(v, -CLIP), CLIP));
        if (kind == 2) {
            Cxy[((size_t)b * T16 + I) * NN + (size_t)J * TB + t] = th;
        } else if (I != J) {
            float* R = (kind == 0) ? Rxx : Ryy;
            R[((size_t)b * T16 + I) * NN + (size_t)J * TB + t] = th;
        }
        if (writeTheta && !diag) {
            const float pv = colpart[0][t] + colpart[1][t] + colpart[2][t] + colpart[3][t];
            const size_t gc = (size_t)I * SARR + (size_t)b * NN + (size_t)J * TB + t;
            colOut[gc] = make_float2(G1, pv);
        }
    }
}

// ---------------------------------------------------------------------------
// Per-step tile kernel with INLINE fan-in combine (split-K last-arriver).
// Wall/Gall double-buffered: stage from {Wr,Gr}, combiner writes {Ww,Gw}.
// ---------------------------------------------------------------------------
struct TileArgsT {
    const unsigned short* Theta;
    const float* Wr; const float* Gr;
    float* Ww; float* Gw;
    const float* Rxx; const float* Ryy; const float* Rxy; const float* Cxy;
    float2* pAX; float2* pBY; float2* pAY; float2* pBX;
    float* ax; float* by; float* ay; float* bx;
    const float* gxw; const float* gyw;
    const float* alpha; const float* beta;
    float* out;
    unsigned int* cnt;
};

__device__ __forceinline__ void combine_group(const TileArgsT& A, int g,
        float eps_ln2, float nieL2E, int do_avg, int do_out, float* aux)
{
    const int tid = threadIdx.x;
    const int o = g >> 7, b = (g >> 4) & 7, K = g & 15;
    const int local = tid >> 1, half = tid & 1;
    const int i = b * NN + K * TB + local;
    const float2* P = (o == 0) ? A.pAX : (o == 1) ? A.pBY : (o == 2) ? A.pAY : A.pBX;
    float* pot = (o == 0) ? A.ax : (o == 1) ? A.by : (o == 2) ? A.ay : A.bx;
    float2 pr[8];
#pragma unroll
    for (int u = 0; u < 8; u++) pr[u] = ld_agent(&P[(size_t)(half * 8 + u) * SARR + i]);
    float M = -3.0e38f;
#pragma unroll
    for (int u = 0; u < 8; u++) M = fmaxf(M, (pr[u].y > 0.f) ? pr[u].x : -3.0e38f);
    float S = 0.f;
#pragma unroll
    for (int u = 0; u < 8; u++)
        S += pr[u].y * __builtin_amdgcn_exp2f(fminf(pr[u].x - M, 0.f));
    const float Mo = __shfl_xor(M, 1);
    const float So = __shfl_xor(S, 1);
    const float nm = fmaxf(M, Mo);
    S = S * __builtin_amdgcn_exp2f(M - nm) + So * __builtin_amdgcn_exp2f(Mo - nm);
    S = fmaxf(S, 1e-38f);
    float r = -eps_ln2 * (nm + __builtin_amdgcn_logf(S));
    if (do_avg) r = 0.5f * (r + pot[i]);
    const int wv = tid >> 6;
    if (do_out) {
        float c = 0.f;
        if (half == 0) {
            const float w = ((o == 0 || o == 3) ? A.alpha : A.beta)[i];
            const float sgn = (o == 0 || o == 1) ? -1.f : 1.f;
            c = sgn * w * r;
        }
        c += __shfl_xor(c, 1);  c += __shfl_xor(c, 2);  c += __shfl_xor(c, 4);
        c += __shfl_xor(c, 8);  c += __shfl_xor(c, 16); c += __shfl_xor(c, 32);
        if ((tid & 63) == 0) aux[wv] = c;
        __syncthreads();
        if (tid == 0) atomicAdd(&A.out[b], aux[0] + aux[1] + aux[2] + aux[3]);
        __syncthreads();
        return;
    }
    if (half == 0) pot[i] = r;
    const float gg = ((o == 0 || o == 3) ? A.gxw : A.gyw)[i] + r * nieL2E;
    float m = gg;
    m = fmaxf(m, __shfl_xor(m, 1));  m = fmaxf(m, __shfl_xor(m, 2));
    m = fmaxf(m, __shfl_xor(m, 4));  m = fmaxf(m, __shfl_xor(m, 8));
    m = fmaxf(m, __shfl_xor(m, 16)); m = fmaxf(m, __shfl_xor(m, 32));
    if ((tid & 63) == 0) aux[wv] = m;
    __syncthreads();
    const float G = fmaxf(fmaxf(aux[0], aux[1]), fmaxf(aux[2], aux[3]));
    if (half == 0) A.Ww[(size_t)o * SARR + i] = __builtin_amdgcn_exp2f(gg - G);
    if (tid == 0) A.Gw[g] = G;
    __syncthreads();
}

__global__ __launch_bounds__(256)
void tile_theta_kernel(TileArgsT A, float ieh, float Kq,
                       float eps_ln2, float nieL2E, int do_avg, int do_out)
{
    __shared__ float2 s1[TB], s2[TB];   // {shift*ieh, W}
    __shared__ float colpart[4][TB];
    __shared__ int bc[2];
    __shared__ float aux[4];
    int kind, I, J; decode_tile(blockIdx.x, kind, I, J);
    const int b = blockIdx.y, t = threadIdx.x;
    const int o1 = (kind == 0) ? 0 : (kind == 1) ? 1 : 3;
    const int o2 = (kind == 0) ? 0 : (kind == 1) ? 1 : 2;
    float2* rowOut = (kind == 0) ? A.pAX : (kind == 1) ? A.pBY : A.pBX;
    float2* colOut = (kind == 0) ? A.pAX : (kind == 1) ? A.pBY : A.pAY;
    const bool diag = (kind < 2) && (I == J);
    const float* W1 = A.Wr + (size_t)o1 * SARR;
    const float* W2 = A.Wr + (size_t)o2 * SARR;
    const float* Rrow = (kind == 0) ? A.Rxx : (kind == 1) ? A.Ryy : A.Rxy;
    const float* Csrc = (kind == 0) ? A.Rxx : (kind == 1) ? A.Ryy : A.Cxy;

    if (t < TB) {
        size_t gi = (size_t)b * NN + (size_t)I * TB + t;
        s1[t] = make_float2(Rrow[((size_t)b * T16 + J) * NN + (size_t)I * TB + t] * ieh, W1[gi]);
    } else {
        int u = t - TB; size_t gi = (size_t)b * NN + (size_t)J * TB + u;
        s2[u] = make_float2(Csrc[((size_t)b * T16 + I) * NN + (size_t)J * TB + u] * ieh, W2[gi]);
    }
    const float G1 = A.Gr[o1 * 128 + b * T16 + I];
    const float G2 = A.Gr[o2 * 128 + b * T16 + J];
    __syncthreads();

    const int lane = t & 63, wv = t >> 6, colg = lane & 7, rowg = lane >> 3;
    const int r0 = wv * 32 + rowg * 4;
    const unsigned short* Tb = A.Theta + ((size_t)(b * NT + blockIdx.x) << 14);

    float srr[4], w1r[4];
#pragma unroll
    for (int rr = 0; rr < 4; rr++) { const float2 v = s1[r0 + rr]; srr[rr] = v.x; w1r[rr] = v.y; }
    float racc[4] = {0.f, 0.f, 0.f, 0.f};
    float cacc[16];
#pragma unroll
    for (int j = 0; j < 16; j++) cacc[j] = 0.f;

    if (diag) {
#pragma unroll
        for (int g = 0; g < 8; g++) {
            const uint4 tq = *(const uint4*)(Tb + th_off(g, wv, lane));
#pragma unroll
            for (int e = 0; e < 2; e++) {
                const int j = g * 2 + e;
                const unsigned int lo = e ? tq.z : tq.x;
                const unsigned int hi = e ? tq.w : tq.y;
                const float2 sv = s2[colg + 8 * j];
                const float thv[4] = {
                    (float)(lo & 0xffffu), (float)(lo >> 16),
                    (float)(hi & 0xffffu), (float)(hi >> 16)
                };
#pragma unroll
                for (int rr = 0; rr < 4; rr++) {
                    const float er = __builtin_amdgcn_exp2f(fmaf(thv[rr], -Kq, srr[rr]));
                    racc[rr] = fmaf(sv.y, er, racc[rr]);
                }
            }
        }
    } else {
#pragma unroll
        for (int g = 0; g < 8; g++) {
            const uint4 tq = *(const uint4*)(Tb + th_off(g, wv, lane));
#pragma unroll
            for (int e = 0; e < 2; e++) {
                const int j = g * 2 + e;
                const unsigned int lo = e ? tq.z : tq.x;
                const unsigned int hi = e ? tq.w : tq.y;
                const float2 sv = s2[colg + 8 * j];
                const float thv[4] = {
                    (float)(lo & 0xffffu), (float)(lo >> 16),
                    (float)(hi & 0xffffu), (float)(hi >> 16)
                };
#pragma unroll
                for (int rr = 0; rr < 4; rr++) {
                    const float er = __builtin_amdgcn_exp2f(fmaf(thv[rr], -Kq, srr[rr]));
                    const float ec = __builtin_amdgcn_exp2f(fmaf(thv[rr], -Kq, sv.x));
                    racc[rr] = fmaf(sv.y, er, racc[rr]);
                    cacc[j]  = fmaf(w1r[rr], ec, cacc[j]);
                }
            }
        }
    }

    // row sums
#pragma unroll
    for (int rr = 0; rr < 4; rr++) {
        float v = racc[rr];
        v += __shfl_xor(v, 1); v += __shfl_xor(v, 2); v += __shfl_xor(v, 4);
        racc[rr] = v;
    }
    if (colg == 0) {
        const size_t gr = (size_t)J * SARR + (size_t)b * NN + (size_t)I * TB + r0;
#pragma unroll
        for (int rr = 0; rr < 4; rr++)
            st_agent(&rowOut[gr + rr], make_float2(G2 - srr[rr], racc[rr]));
    }
    if (!diag) {
        // col sums
#pragma unroll
        for (int j = 0; j < 16; j++) {
            float v = cacc[j];
            v += __shfl_xor(v, 8); v += __shfl_xor(v, 16); v += __shfl_xor(v, 32);
            cacc[j] = v;
        }
        if (rowg == 0) {
#pragma unroll
            for (int j = 0; j < 16; j++) colpart[wv][colg + 8 * j] = cacc[j];
        }
        __syncthreads();
        if (t < TB) {
            const float v = colpart[0][t] + colpart[1][t] + colpart[2][t] + colpart[3][t];
            const size_t gc = (size_t)I * SARR + (size_t)b * NN + (size_t)J * TB + t;
            st_agent(&colOut[gc], make_float2(G1 - s2[t].x, v));
        }
    }

    // ---- fan-in: bump counters (after all stores drained by the barrier) ----
    __syncthreads();
    const int oR = (kind == 0) ? 0 : (kind == 1) ? 1 : 3;
    const int oC = (kind == 0) ? 0 : (kind == 1) ? 1 : 2;
    const int gA = oR * 128 + b * 16 + I;
    const int gB = oC * 128 + b * 16 + J;
    if (t == 0) {
        bc[0] = (int)__hip_atomic_fetch_add(&A.cnt[gA], 1u,
                    __ATOMIC_ACQ_REL, __HIP_MEMORY_SCOPE_AGENT);
        bc[1] = diag ? -1
                     : (int)__hip_atomic_fetch_add(&A.cnt[gB], 1u,
                    __ATOMIC_ACQ_REL, __HIP_MEMORY_SCOPE_AGENT);
    }
    __syncthreads();
    const int oldA = bc[0], oldB = bc[1];
    if (oldA == 15) {
        combine_group(A, gA, eps_ln2, nieL2E, do_avg, do_out, aux);
        if (t == 0) __hip_atomic_store(&A.cnt[gA], 0u, __ATOMIC_RELAXED,
                                       __HIP_MEMORY_SCOPE_AGENT);
    }
    if (oldB == 15) {
        combine_group(A, gB, eps_ln2, nieL2E, do_avg, do_out, aux);
        if (t == 0) __hip_atomic_store(&A.cnt[gB], 0u, __ATOMIC_RELAXED,
                                       __HIP_MEMORY_SCOPE_AGENT);
    }
}

// ---------------------------------------------------------------------------
// OLD tile kernel kept verbatim as fallback when ws_size can't hold theta.
// ---------------------------------------------------------------------------
struct TileArgs {
    const float* x; const float* y;
    const float* Wall; const float* Gall;
    const float* Rxx; const float* Ryy; const float* Rxy; const float* Cxy;
    float2* pAX; float2* pBY; float2* pAY; float2* pBX;
};

__global__ __launch_bounds__(256)
void tile_kernel(TileArgs A, float ieh, float pi_ieh)
{
    __shared__ float4 p1s[TB], p2s[TB];
    __shared__ float srs[TB], scs[TB];
    __shared__ float colpart[4][TB];
    int kind, I, J; decode_tile(blockIdx.x, kind, I, J);
    const int b = blockIdx.y, t = threadIdx.x;
    const float* P1 = (kind == 1) ? A.y : A.x;
    const float* P2 = (kind == 0) ? A.x : A.y;
    const int o1 = (kind == 0) ? 0 : (kind == 1) ? 1 : 3;
    const int o2 = (kind == 0) ? 0 : (kind == 1) ? 1 : 2;
    float2* rowOut = (kind == 0) ? A.pAX : (kind == 1) ? A.pBY : A.pBX;
    float2* colOut = (kind == 0) ? A.pAX : (kind == 1) ? A.pBY : A.pAY;
    const bool diag = (kind < 2) && (I == J);
    const float* W1 = A.Wall + (size_t)o1 * SARR;
    const float* W2 = A.Wall + (size_t)o2 * SARR;
    const float* Rrow = (kind == 0) ? A.Rxx : (kind == 1) ? A.Ryy : A.Rxy;
    const float* Csrc = (kind == 0) ? A.Rxx : (kind == 1) ? A.Ryy : A.Cxy;

    const float K0 = 1.5707288f * ieh, K1 = -0.2121144f * ieh;
    const float K2 = 0.0742610f * ieh, K3 = -0.0187293f * ieh;

    if (t < TB) {
        size_t gi = (size_t)b * NN + (size_t)I * TB + t;
        p1s[t] = make_float4(P1[gi * 3], P1[gi * 3 + 1], P1[gi * 3 + 2], W1[gi]);
        srs[t] = Rrow[((size_t)b * T16 + J) * NN + (size_t)I * TB + t] * ieh;
    } else {
        int u = t - TB; size_t gi = (size_t)b * NN + (size_t)J * TB + u;
        p2s[u] = make_float4(P2[gi * 3], P2[gi * 3 + 1], P2[gi * 3 + 2], W2[gi]);
        scs[u] = Csrc[((size_t)b * T16 + I) * NN + (size_t)J * TB + u] * ieh;
    }
    const float G1 = A.Gall[o1 * 128 + b * T16 + I];
    const float G2 = A.Gall[o2 * 128 + b * T16 + J];
    __syncthreads();

    const int lane = t & 63, wv = t >> 6, colg = lane & 7, rowg = lane >> 3;
    const int r0 = wv * 32 + rowg * 4;
    float4 pr[4]; float srr[4];
#pragma unroll
    for (int rr = 0; rr < 4; rr++) { pr[rr] = p1s[r0 + rr]; srr[rr] = srs[r0 + rr]; }
    float racc[4] = {0.f, 0.f, 0.f, 0.f};
    float cacc[16];
#pragma unroll
    for (int j = 0; j < 16; j++) cacc[j] = 0.f;

#pragma unroll
    for (int j = 0; j < 16; j++) {
        const float4 q = p2s[colg + 8 * j];
        const float sc = scs[colg + 8 * j];
#pragma unroll
        for (int rr = 0; rr < 4; rr++) {
            const float4 p = pr[rr];
            float d = fmaf(p.x, q.x, fmaf(p.y, q.y, p.z * q.z));
            d = fminf(fmaxf(d, -CLIP), CLIP);
            const float u = fabsf(d);
            float pl = fmaf(u, K3, K2); pl = fmaf(u, pl, K1); pl = fmaf(u, pl, K0);
            const float rt = __builtin_amdgcn_sqrtf(1.f - u) * pl;
            const float ach = (d >= 0.f) ? rt : (pi_ieh - rt);
            racc[rr] = fmaf(q.w, __builtin_amdgcn_exp2f(srr[rr] - ach), racc[rr]);
            cacc[j]  = fmaf(p.w, __builtin_amdgcn_exp2f(sc - ach), cacc[j]);
        }
    }

#pragma unroll
    for (int j = 0; j < 16; j++) {
        float v = cacc[j];
        v += __shfl_xor(v, 8); v += __shfl_xor(v, 16); v += __shfl_xor(v, 32);
        cacc[j] = v;
    }
    if (rowg == 0) {
#pragma unroll
        for (int j = 0; j < 16; j++) colpart[wv][colg + 8 * j] = cacc[j];
    }
#pragma unroll
    for (int rr = 0; rr < 4; rr++) {
        float v = racc[rr];
        v += __shfl_xor(v, 1); v += __shfl_xor(v, 2); v += __shfl_xor(v, 4);
        racc[rr] = v;
    }
    if (colg == 0) {
        const size_t gr = (size_t)J * SARR + (size_t)b * NN + (size_t)I * TB + r0;
#pragma unroll
        for (int rr = 0; rr < 4; rr++)
            rowOut[gr + rr] = make_float2(G2 - srr[rr], racc[rr]);
    }
    __syncthreads();
    if (!diag && t < TB) {
        const float v = colpart[0][t] + colpart[1][t] + colpart[2][t] + colpart[3][t];
        const size_t gc = (size_t)I * SARR + (size_t)b * NN + (size_t)J * TB + t;
        colOut[gc] = make_float2(G1 - scs[t], v);
    }
}

// ---------------------------------------------------------------------------
// standalone combine (init step + fallback path)
// ---------------------------------------------------------------------------
__global__ __launch_bounds__(256)
void combine_kernel(const float2* __restrict__ pAX, const float2* __restrict__ pBY,
                    const float2* __restrict__ pAY, const float2* __restrict__ pBX,
                    float* __restrict__ ax, float* __restrict__ by,
                    float* __restrict__ ay, float* __restrict__ bx,
                    const float* __restrict__ gxw, const float* __restrict__ gyw,
                    float* __restrict__ Wall, float* __restrict__ Gall,
                    float eps_ln2, float nieL2E, int do_avg)
{
    const int tid = threadIdx.x;
    const int gid = blockIdx.x * 256 + tid;
    const int o = gid >> 14, i = gid & (SARR - 1);
    const float2* P = (o == 0) ? pAX : (o == 1) ? pBY : (o == 2) ? pAY : pBX;
    float* pot = (o == 0) ? ax : (o == 1) ? by : (o == 2) ? ay : bx;
    float2 pr[T16];
#pragma unroll
    for (int u = 0; u < T16; u++) pr[u] = P[(size_t)u * SARR + i];
    float M = -3.0e38f;
#pragma unroll
    for (int u = 0; u < T16; u++) M = fmaxf(M, (pr[u].y > 0.f) ? pr[u].x : -3.0e38f);
    float S = 0.f;
#pragma unroll
    for (int u = 0; u < T16; u++)
        S += pr[u].y * __builtin_amdgcn_exp2f(fminf(pr[u].x - M, 0.f));
    S = fmaxf(S, 1e-38f);
    float r = -eps_ln2 * (M + __builtin_amdgcn_logf(S));
    if (do_avg) r = 0.5f * (r + pot[i]);
    pot[i] = r;
    const float g = ((o == 0 || o == 3) ? gxw[i] : gyw[i]) + r * nieL2E;
    float m = g;
    m = fmaxf(m, __shfl_xor(m, 1));  m = fmaxf(m, __shfl_xor(m, 2));
    m = fmaxf(m, __shfl_xor(m, 4));  m = fmaxf(m, __shfl_xor(m, 8));
    m = fmaxf(m, __shfl_xor(m, 16)); m = fmaxf(m, __shfl_xor(m, 32));
    __shared__ float wmax[4];
    const int wv = tid >> 6;
    if ((tid & 63) == 0) wmax[wv] = m;
    __syncthreads();
    const int grp = tid >> 7;
    const float G = fmaxf(wmax[grp * 2], wmax[grp * 2 + 1]);
    Wall[gid] = __builtin_amdgcn_exp2f(g - G);
    if ((tid & 127) == 0) Gall[gid >> 7] = G;
}

// ---------------------------------------------------------------------------
__global__ __launch_bounds__(256)
void reduce_kernel(const float* __restrict__ alpha, const float* __restrict__ beta,
                   const float* __restrict__ a_x, const float* __restrict__ b_x,
                   const float* __restrict__ a_y, const float* __restrict__ b_y,
                   float* __restrict__ out)
{
    const int b = blockIdx.x, tid = threadIdx.x;
    float acc = 0.f;
    for (int n = tid; n < NN; n += 256) {
        const size_t i = (size_t)b * NN + n;
        acc += alpha[i] * (b_x[i] - a_x[i]);
        acc += beta[i] * (a_y[i] - b_y[i]);
    }
    __shared__ float red[256];
    red[tid] = acc;
    __syncthreads();
    for (int st = 128; st > 0; st >>= 1) {
        if (tid < st) red[tid] += red[tid + st];
        __syncthreads();
    }
    if (tid == 0) out[b] = red[0];
}

// ---------------------------------------------------------------------------
extern "C" void kernel_launch(void* const* d_in, const int* in_sizes, int n_in,
                              void* d_out, int out_size, void* d_ws, size_t ws_size,
                              hipStream_t stream)
{
    const float* alpha = (const float*)d_in[0];
    const float* x     = (const float*)d_in[1];
    const float* beta  = (const float*)d_in[2];
    const float* y     = (const float*)d_in[3];
    float* out = (float*)d_out;
    float* ws  = (float*)d_ws;

    const size_t S = SARR;
    float* gxw   = ws;
    float* gyw   = ws + S;
    float* ax    = ws + 2 * S;
    float* by    = ws + 3 * S;
    float* ay    = ws + 4 * S;
    float* bx    = ws + 5 * S;
    float* Wall0 = ws + 6 * S;             // 4*S
    float* Wall1 = ws + 10 * S;            // 4*S
    float* Gall0 = ws + 14 * S;            // 512
    float* Gall1 = ws + 14 * S + 512;      // 512
    unsigned int* cnt = (unsigned int*)(ws + 14 * S + 1024);  // 512
    float* Rxx   = ws + 14 * S + 1536;     // 16*S each
    float* Ryy   = Rxx + 16 * S;
    float* Rxy   = Ryy + 16 * S;
    float* Cxy   = Rxy + 16 * S;
    float* pb    = Cxy + 16 * S;
    const size_t PSZ = (size_t)SARR * T16;
    float2* pAX = (float2*)pb;
    float2* pBY = pAX + PSZ;
    float2* pAY = pBY + PSZ;
    float2* pBX = pAY + PSZ;

    float* thetaF = pb + (size_t)8 * PSZ;
    unsigned short* Theta = (unsigned short*)thetaF;
    const size_t used_bytes  = (size_t)((char*)thetaF - (char*)ws);
    const size_t theta_bytes = (size_t)BB * NT * 16384 * sizeof(unsigned short); // ~138 MB
    const int useTheta = (ws_size >= used_bytes + theta_bytes) ? 1 : 0;

    const float EPS[8] = {4.0f, 4.0f, 1.0f, 0.25f, 0.0625f, 0.015625f, 0.00390625f, 0.0025f};

    pack_kernel<<<(4 * SARR) / 256, 256, 0, stream>>>(alpha, beta, gxw, gyw,
                                                      Wall0, Gall0, out, cnt);
    const float negK = -0.5f * (1.f / EPS[0]) * L2E;
    maxes_kernel<<<dim3(NT, BB), 256, 0, stream>>>(x, y, Rxx, Ryy, Rxy, Cxy, Theta,
                                                   Wall0, Gall0, pAX, pBY, pAY, pBX,
                                                   negK, useTheta);

    if (useTheta) {
        // init combine: reads maxes partials, writes buf0 (avg=0)
        combine_kernel<<<(4 * SARR) / 256, 256, 0, stream>>>(
            pAX, pBY, pAY, pBX, ax, by, ay, bx, gxw, gyw, Wall0, Gall0,
            EPS[0] * LN2, (1.f / EPS[0]) * L2E, 0);

        TileArgsT TT;
        TT.Theta = Theta;
        TT.Rxx = Rxx; TT.Ryy = Ryy; TT.Rxy = Rxy; TT.Cxy = Cxy;
        TT.pAX = pAX; TT.pBY = pBY; TT.pAY = pAY; TT.pBX = pBX;
        TT.ax = ax; TT.by = by; TT.ay = ay; TT.bx = bx;
        TT.gxw = gxw; TT.gyw = gyw;
        TT.alpha = alpha; TT.beta = beta;
        TT.out = out; TT.cnt = cnt;

        // 9 fused tile+combine passes; double-buffered W/G
        for (int p = 0; p < 9; p++) {
            const float e      = (p < 8) ? EPS[p] : EPS[7];
            const float next_e = (p < 7) ? EPS[p + 1] : EPS[7];
            const int avg      = (p < 8) ? 1 : 0;
            const int douts    = (p == 8) ? 1 : 0;
            const float ieh = 0.5f * (1.f / e) * L2E;
            TT.Wr = (p & 1) ? Wall1 : Wall0;
            TT.Gr = (p & 1) ? Gall1 : Gall0;
            TT.Ww = (p & 1) ? Wall0 : Wall1;
            TT.Gw = (p & 1) ? Gall0 : Gall1;
            tile_theta_kernel<<<dim3(NT, BB), 256, 0, stream>>>(
                TT, ieh, ieh * THSCI, e * LN2, (1.f / next_e) * L2E, avg, douts);
        }
    } else {
        // fallback: original recompute path with separate combines
        TileArgs TA;
        TA.x = x; TA.y = y; TA.Wall = Wall0; TA.Gall = Gall0;
        TA.Rxx = Rxx; TA.Ryy = Ryy; TA.Rxy = Rxy; TA.Cxy = Cxy;
        TA.pAX = pAX; TA.pBY = pBY; TA.pAY = pAY; TA.pBX = pBX;
        auto step = [&](float e, float next_e, int avg, int run_tile) {
            const float ieh = 0.5f * (1.f / e) * L2E;
            if (run_tile)
                tile_kernel<<<dim3(NT, BB), 256, 0, stream>>>(TA, ieh, PI_F * ieh);
            combine_kernel<<<(4 * SARR) / 256, 256, 0, stream>>>(
                pAX, pBY, pAY, pBX, ax, by, ay, bx, gxw, gyw, Wall0, Gall0,
                e * LN2, (1.f / next_e) * L2E, avg);
        };
        step(EPS[0], EPS[0], 0, 1);
        for (int k = 0; k < 8; k++) step(EPS[k], (k < 7) ? EPS[k + 1] : EPS[7], 1, 1);
        step(EPS[7], EPS[7], 0, 1);
        reduce_kernel<<<BB, 256, 0, stream>>>(alpha, beta, ax, bx, ay, by, out);
    }
}

// Round 9
// 388.875 us; speedup vs baseline: 6.2871x; 6.2871x over previous
//
#include <hip/hip_runtime.h>
#include <math.h>

// Problem constants: B=8, N=M=2048, D=3.
#define BB 8
#define NN 2048
#define L2E 1.4426950408889634f
#define LN2 0.6931471805599453f
#define PI_F 3.14159265358979f
#define CLIP 0.999999f
#define THSC 20860.0f            // u16 quantization scale, pi*THSC = 65533.6 < 65535
#define THSCI (1.0f / 20860.0f)

constexpr int TB   = 128;
constexpr int T16  = NN / TB;              // 16
constexpr int NXX  = T16 * (T16 + 1) / 2;  // 136
constexpr int NT   = 2 * NXX + T16 * T16;  // 528 tiles per batch
constexpr int SARR = BB * NN;              // 16384

// tile index -> (kind, I, J). kind 0: xx (I<=J), 1: yy (I<=J), 2: xy (all)
__device__ __forceinline__ void decode_tile(int bx, int& kind, int& I, int& J) {
    if (bx < NXX) kind = 0;
    else if (bx < 2 * NXX) { kind = 1; bx -= NXX; }
    else { kind = 2; bx -= 2 * NXX; }
    if (kind < 2) {
        int idx = bx; I = 0;
        for (;;) { int len = T16 - I; if (idx < len) { J = I + idx; break; } idx -= len; I++; }
    } else { I = bx >> 4; J = bx & 15; }
}

// raw acos via A&S 4.4.45 (|err| <= 7e-5 rad), input pre-clipped
__device__ __forceinline__ float acos_raw(float d) {
    const float u = fabsf(d);
    float pl = fmaf(u, -0.0187293f, 0.0742610f);
    pl = fmaf(u, pl, -0.2121144f); pl = fmaf(u, pl, 1.5707288f);
    const float rt = __builtin_amdgcn_sqrtf(1.f - u) * pl;
    return (d >= 0.f) ? rt : (PI_F - rt);
}

// theta flat offset (u16 units) — SAME formula producer & consumer.
__device__ __forceinline__ size_t th_off(int g, int wv, int lane) {
    return (size_t)(((g * 4 + wv) * 64 + lane) * 8);
}

// ---------------------------------------------------------------------------
// pack: initial g = log_weights * log2(e); emit W = 2^{g-G}, per-128-block G.
// Also zeroes out[] (final combine atomically accumulates into it).
// ---------------------------------------------------------------------------
__global__ __launch_bounds__(256)
void pack_kernel(const float* __restrict__ alpha, const float* __restrict__ beta,
                 float* __restrict__ gxw, float* __restrict__ gyw,
                 float* __restrict__ Wall, float* __restrict__ Gall,
                 float* __restrict__ out)
{
    const int tid = threadIdx.x;
    const int gid = blockIdx.x * 256 + tid;
    if (blockIdx.x == 0 && tid < BB) out[tid] = 0.f;
    const int o = gid >> 14, i = gid & (SARR - 1);
    const float* w = (o == 0 || o == 3) ? alpha : beta;
    const float v = w[i];
    const float g = ((v > 0.f) ? logf(fmaxf(v, 1e-30f)) : -1e5f) * L2E;
    if (o == 0) gxw[i] = g;
    if (o == 1) gyw[i] = g;
    float m = g;
    m = fmaxf(m, __shfl_xor(m, 1));  m = fmaxf(m, __shfl_xor(m, 2));
    m = fmaxf(m, __shfl_xor(m, 4));  m = fmaxf(m, __shfl_xor(m, 8));
    m = fmaxf(m, __shfl_xor(m, 16)); m = fmaxf(m, __shfl_xor(m, 32));
    __shared__ float wmax[4];
    const int wv = tid >> 6;
    if ((tid & 63) == 0) wmax[wv] = m;
    __syncthreads();
    const int grp = tid >> 7;
    const float G = fmaxf(wmax[grp * 2], wmax[grp * 2 + 1]);
    Wall[gid] = __builtin_amdgcn_exp2f(g - G);
    if ((tid & 127) == 0) Gall[gid >> 7] = G;
}

// ---------------------------------------------------------------------------
// One-time geometry pass + FUSED INIT STEP (eps=4: no shift needed, one exp2
// per pair serves both reduction directions). Also writes quantized theta.
// ---------------------------------------------------------------------------
__global__ __launch_bounds__(256)
void maxes_kernel(const float* __restrict__ x, const float* __restrict__ y,
                  float* __restrict__ Rxx, float* __restrict__ Ryy,
                  float* __restrict__ Rxy, float* __restrict__ Cxy,
                  unsigned short* __restrict__ Theta,
                  const float* __restrict__ Wall, const float* __restrict__ Gall,
                  float2* pAX, float2* pBY, float2* pAY, float2* pBX,
                  float negK, int writeTheta)
{
    __shared__ float4 p1s[TB], p2s[TB];
    __shared__ float colred[4][TB];
    __shared__ float colpart[4][TB];
    int kind, I, J; decode_tile(blockIdx.x, kind, I, J);
    const int b = blockIdx.y, t = threadIdx.x;
    const float* P1 = (kind == 1) ? y : x;
    const float* P2 = (kind == 0) ? x : y;
    const int o1 = (kind == 0) ? 0 : (kind == 1) ? 1 : 3;
    const int o2 = (kind == 0) ? 0 : (kind == 1) ? 1 : 2;
    float2* rowOut = (kind == 0) ? pAX : (kind == 1) ? pBY : pBX;
    float2* colOut = (kind == 0) ? pAX : (kind == 1) ? pBY : pAY;
    const bool diag = (kind < 2) && (I == J);
    const float* W1 = Wall + (size_t)o1 * SARR;
    const float* W2 = Wall + (size_t)o2 * SARR;

    if (t < TB) {
        size_t gi = (size_t)b * NN + (size_t)I * TB + t;
        p1s[t] = make_float4(P1[gi * 3], P1[gi * 3 + 1], P1[gi * 3 + 2], W1[gi]);
    } else {
        int u = t - TB; size_t gi = (size_t)b * NN + (size_t)J * TB + u;
        p2s[u] = make_float4(P2[gi * 3], P2[gi * 3 + 1], P2[gi * 3 + 2], W2[gi]);
    }
    const float G1 = Gall[o1 * 128 + b * T16 + I];
    const float G2 = Gall[o2 * 128 + b * T16 + J];
    __syncthreads();
    const int lane = t & 63, wv = t >> 6, colg = lane & 7, rowg = lane >> 3;
    const int r0 = wv * 32 + rowg * 4;
    unsigned short* Tb = Theta + ((size_t)(b * NT + blockIdx.x) << 14);

    float4 pr[4];
#pragma unroll
    for (int rr = 0; rr < 4; rr++) pr[rr] = p1s[r0 + rr];
    float rmx[4] = {-2.f, -2.f, -2.f, -2.f};
    float cmx[16];
#pragma unroll
    for (int j = 0; j < 16; j++) cmx[j] = -2.f;
    float racc[4] = {0.f, 0.f, 0.f, 0.f};
    float cacc[16];
#pragma unroll
    for (int j = 0; j < 16; j++) cacc[j] = 0.f;

#pragma unroll
    for (int g = 0; g < 8; g++) {
        uint4 outv;
#pragma unroll
        for (int e = 0; e < 2; e++) {
            const int j = g * 2 + e;
            const float4 q = p2s[colg + 8 * j];
            unsigned int lo = 0, hi = 0;
#pragma unroll
            for (int rr = 0; rr < 4; rr++) {
                const float d = fmaf(pr[rr].x, q.x, fmaf(pr[rr].y, q.y, pr[rr].z * q.z));
                rmx[rr] = fmaxf(rmx[rr], d);
                cmx[j] = fmaxf(cmx[j], d);
                if (writeTheta) {
                    const float dc = fminf(fmaxf(d, -CLIP), CLIP);
                    const float th = acos_raw(dc);
                    const unsigned int qv = __float2uint_rn(th * THSC);
                    if (rr == 0) lo = qv;
                    else if (rr == 1) lo |= qv << 16;
                    else if (rr == 2) hi = qv;
                    else hi |= qv << 16;
                    // fused init step (eps=4, shift-free): one exp2, both dirs
                    const float em = __builtin_amdgcn_exp2f(th * negK);
                    racc[rr] = fmaf(q.w, em, racc[rr]);
                    cacc[j]  = fmaf(pr[rr].w, em, cacc[j]);
                }
            }
            if (e == 0) { outv.x = lo; outv.y = hi; }
            else        { outv.z = lo; outv.w = hi; }
        }
        if (writeTheta)
            *(uint4*)(Tb + th_off(g, wv, lane)) = outv;
    }

    // ---- max reductions (R arrays) ----
#pragma unroll
    for (int rr = 0; rr < 4; rr++) {
        float v = rmx[rr];
        v = fmaxf(v, __shfl_xor(v, 1)); v = fmaxf(v, __shfl_xor(v, 2));
        v = fmaxf(v, __shfl_xor(v, 4));
        rmx[rr] = v;
    }
    if (colg == 0) {
        float* R = (kind == 0) ? Rxx : (kind == 1) ? Ryy : Rxy;
        const size_t base = ((size_t)b * T16 + J) * NN + (size_t)I * TB + r0;
#pragma unroll
        for (int rr = 0; rr < 4; rr++)
            R[base + rr] = acos_raw(fminf(fmaxf(rmx[rr], -CLIP), CLIP));
    }
#pragma unroll
    for (int j = 0; j < 16; j++) {
        float v = cmx[j];
        v = fmaxf(v, __shfl_xor(v, 8)); v = fmaxf(v, __shfl_xor(v, 16));
        v = fmaxf(v, __shfl_xor(v, 32));
        cmx[j] = v;
    }
    if (rowg == 0) {
#pragma unroll
        for (int j = 0; j < 16; j++) colred[wv][colg + 8 * j] = cmx[j];
    }

    // ---- init-step partial reductions ----
    if (writeTheta) {
#pragma unroll
        for (int j = 0; j < 16; j++) {
            float v = cacc[j];
            v += __shfl_xor(v, 8); v += __shfl_xor(v, 16); v += __shfl_xor(v, 32);
            cacc[j] = v;
        }
        if (rowg == 0) {
#pragma unroll
            for (int j = 0; j < 16; j++) colpart[wv][colg + 8 * j] = cacc[j];
        }
#pragma unroll
        for (int rr = 0; rr < 4; rr++) {
            float v = racc[rr];
            v += __shfl_xor(v, 1); v += __shfl_xor(v, 2); v += __shfl_xor(v, 4);
            racc[rr] = v;
        }
        if (colg == 0) {
            const size_t gr = (size_t)J * SARR + (size_t)b * NN + (size_t)I * TB + r0;
#pragma unroll
            for (int rr = 0; rr < 4; rr++)
                rowOut[gr + rr] = make_float2(G2, racc[rr]);
        }
    }

    __syncthreads();
    if (t < TB) {
        const float v = fmaxf(fmaxf(colred[0][t], colred[1][t]),
                              fmaxf(colred[2][t], colred[3][t]));
        const float th = acos_raw(fminf(fmaxf(v, -CLIP), CLIP));
        if (kind == 2) {
            Cxy[((size_t)b * T16 + I) * NN + (size_t)J * TB + t] = th;
        } else if (I != J) {
            float* R = (kind == 0) ? Rxx : Ryy;
            R[((size_t)b * T16 + I) * NN + (size_t)J * TB + t] = th;
        }
        if (writeTheta && !diag) {
            const float pv = colpart[0][t] + colpart[1][t] + colpart[2][t] + colpart[3][t];
            const size_t gc = (size_t)I * SARR + (size_t)b * NN + (size_t)J * TB + t;
            colOut[gc] = make_float2(G1, pv);
        }
    }
}

// ---------------------------------------------------------------------------
// Per-step tile kernel (r7 verbatim: in-loop uint4 theta reads, two exp2 per
// pair, shifts in registers, diag specialization).
// ---------------------------------------------------------------------------
struct TileArgsT {
    const unsigned short* Theta;
    const float* Wall; const float* Gall;
    const float* Rxx; const float* Ryy; const float* Rxy; const float* Cxy;
    float2* pAX; float2* pBY; float2* pAY; float2* pBX;
};

__global__ __launch_bounds__(256)
void tile_theta_kernel(TileArgsT A, float ieh, float Kq)
{
    __shared__ float2 s1[TB], s2[TB];   // {shift*ieh, W}
    __shared__ float colpart[4][TB];
    int kind, I, J; decode_tile(blockIdx.x, kind, I, J);
    const int b = blockIdx.y, t = threadIdx.x;
    const int o1 = (kind == 0) ? 0 : (kind == 1) ? 1 : 3;
    const int o2 = (kind == 0) ? 0 : (kind == 1) ? 1 : 2;
    float2* rowOut = (kind == 0) ? A.pAX : (kind == 1) ? A.pBY : A.pBX;
    float2* colOut = (kind == 0) ? A.pAX : (kind == 1) ? A.pBY : A.pAY;
    const bool diag = (kind < 2) && (I == J);
    const float* W1 = A.Wall + (size_t)o1 * SARR;
    const float* W2 = A.Wall + (size_t)o2 * SARR;
    const float* Rrow = (kind == 0) ? A.Rxx : (kind == 1) ? A.Ryy : A.Rxy;
    const float* Csrc = (kind == 0) ? A.Rxx : (kind == 1) ? A.Ryy : A.Cxy;

    if (t < TB) {
        size_t gi = (size_t)b * NN + (size_t)I * TB + t;
        s1[t] = make_float2(Rrow[((size_t)b * T16 + J) * NN + (size_t)I * TB + t] * ieh, W1[gi]);
    } else {
        int u = t - TB; size_t gi = (size_t)b * NN + (size_t)J * TB + u;
        s2[u] = make_float2(Csrc[((size_t)b * T16 + I) * NN + (size_t)J * TB + u] * ieh, W2[gi]);
    }
    const float G1 = A.Gall[o1 * 128 + b * T16 + I];
    const float G2 = A.Gall[o2 * 128 + b * T16 + J];
    __syncthreads();

    const int lane = t & 63, wv = t >> 6, colg = lane & 7, rowg = lane >> 3;
    const int r0 = wv * 32 + rowg * 4;
    const unsigned short* Tb = A.Theta + ((size_t)(b * NT + blockIdx.x) << 14);

    float srr[4], w1r[4];
#pragma unroll
    for (int rr = 0; rr < 4; rr++) { const float2 v = s1[r0 + rr]; srr[rr] = v.x; w1r[rr] = v.y; }
    float racc[4] = {0.f, 0.f, 0.f, 0.f};
    float cacc[16];
#pragma unroll
    for (int j = 0; j < 16; j++) cacc[j] = 0.f;

    if (diag) {
        // symmetric diagonal tile: col sums identical to row sums — skip cacc
#pragma unroll
        for (int g = 0; g < 8; g++) {
            const uint4 tq = *(const uint4*)(Tb + th_off(g, wv, lane));
#pragma unroll
            for (int e = 0; e < 2; e++) {
                const int j = g * 2 + e;
                const unsigned int lo = e ? tq.z : tq.x;
                const unsigned int hi = e ? tq.w : tq.y;
                const float2 sv = s2[colg + 8 * j];
                const float thv[4] = {
                    (float)(lo & 0xffffu), (float)(lo >> 16),
                    (float)(hi & 0xffffu), (float)(hi >> 16)
                };
#pragma unroll
                for (int rr = 0; rr < 4; rr++) {
                    const float er = __builtin_amdgcn_exp2f(fmaf(thv[rr], -Kq, srr[rr]));
                    racc[rr] = fmaf(sv.y, er, racc[rr]);
                }
            }
        }
    } else {
#pragma unroll
        for (int g = 0; g < 8; g++) {
            const uint4 tq = *(const uint4*)(Tb + th_off(g, wv, lane));
#pragma unroll
            for (int e = 0; e < 2; e++) {
                const int j = g * 2 + e;
                const unsigned int lo = e ? tq.z : tq.x;
                const unsigned int hi = e ? tq.w : tq.y;
                const float2 sv = s2[colg + 8 * j];
                const float thv[4] = {
                    (float)(lo & 0xffffu), (float)(lo >> 16),
                    (float)(hi & 0xffffu), (float)(hi >> 16)
                };
#pragma unroll
                for (int rr = 0; rr < 4; rr++) {
                    const float er = __builtin_amdgcn_exp2f(fmaf(thv[rr], -Kq, srr[rr]));
                    const float ec = __builtin_amdgcn_exp2f(fmaf(thv[rr], -Kq, sv.x));
                    racc[rr] = fmaf(sv.y, er, racc[rr]);
                    cacc[j]  = fmaf(w1r[rr], ec, cacc[j]);
                }
            }
        }
    }

    // row sums: reduce across colg (lane bits 0..2)
#pragma unroll
    for (int rr = 0; rr < 4; rr++) {
        float v = racc[rr];
        v += __shfl_xor(v, 1); v += __shfl_xor(v, 2); v += __shfl_xor(v, 4);
        racc[rr] = v;
    }
    if (colg == 0) {
        const size_t gr = (size_t)J * SARR + (size_t)b * NN + (size_t)I * TB + r0;
#pragma unroll
        for (int rr = 0; rr < 4; rr++)
            rowOut[gr + rr] = make_float2(G2 - srr[rr], racc[rr]);
    }
    if (!diag) {
        // col sums: reduce across rowg (lane bits 3..5)
#pragma unroll
        for (int j = 0; j < 16; j++) {
            float v = cacc[j];
            v += __shfl_xor(v, 8); v += __shfl_xor(v, 16); v += __shfl_xor(v, 32);
            cacc[j] = v;
        }
        if (rowg == 0) {
#pragma unroll
            for (int j = 0; j < 16; j++) colpart[wv][colg + 8 * j] = cacc[j];
        }
        __syncthreads();
        if (t < TB) {
            const float v = colpart[0][t] + colpart[1][t] + colpart[2][t] + colpart[3][t];
            const size_t gc = (size_t)I * SARR + (size_t)b * NN + (size_t)J * TB + t;
            colOut[gc] = make_float2(G1 - s2[t].x, v);
        }
    }
}

// ---------------------------------------------------------------------------
// OLD tile kernel kept verbatim as fallback when ws_size can't hold theta.
// ---------------------------------------------------------------------------
struct TileArgs {
    const float* x; const float* y;
    const float* Wall; const float* Gall;
    const float* Rxx; const float* Ryy; const float* Rxy; const float* Cxy;
    float2* pAX; float2* pBY; float2* pAY; float2* pBX;
};

__global__ __launch_bounds__(256)
void tile_kernel(TileArgs A, float ieh, float pi_ieh)
{
    __shared__ float4 p1s[TB], p2s[TB];
    __shared__ float srs[TB], scs[TB];
    __shared__ float colpart[4][TB];
    int kind, I, J; decode_tile(blockIdx.x, kind, I, J);
    const int b = blockIdx.y, t = threadIdx.x;
    const float* P1 = (kind == 1) ? A.y : A.x;
    const float* P2 = (kind == 0) ? A.x : A.y;
    const int o1 = (kind == 0) ? 0 : (kind == 1) ? 1 : 3;
    const int o2 = (kind == 0) ? 0 : (kind == 1) ? 1 : 2;
    float2* rowOut = (kind == 0) ? A.pAX : (kind == 1) ? A.pBY : A.pBX;
    float2* colOut = (kind == 0) ? A.pAX : (kind == 1) ? A.pBY : A.pAY;
    const bool diag = (kind < 2) && (I == J);
    const float* W1 = A.Wall + (size_t)o1 * SARR;
    const float* W2 = A.Wall + (size_t)o2 * SARR;
    const float* Rrow = (kind == 0) ? A.Rxx : (kind == 1) ? A.Ryy : A.Rxy;
    const float* Csrc = (kind == 0) ? A.Rxx : (kind == 1) ? A.Ryy : A.Cxy;

    const float K0 = 1.5707288f * ieh, K1 = -0.2121144f * ieh;
    const float K2 = 0.0742610f * ieh, K3 = -0.0187293f * ieh;

    if (t < TB) {
        size_t gi = (size_t)b * NN + (size_t)I * TB + t;
        p1s[t] = make_float4(P1[gi * 3], P1[gi * 3 + 1], P1[gi * 3 + 2], W1[gi]);
        srs[t] = Rrow[((size_t)b * T16 + J) * NN + (size_t)I * TB + t] * ieh;
    } else {
        int u = t - TB; size_t gi = (size_t)b * NN + (size_t)J * TB + u;
        p2s[u] = make_float4(P2[gi * 3], P2[gi * 3 + 1], P2[gi * 3 + 2], W2[gi]);
        scs[u] = Csrc[((size_t)b * T16 + I) * NN + (size_t)J * TB + u] * ieh;
    }
    const float G1 = A.Gall[o1 * 128 + b * T16 + I];
    const float G2 = A.Gall[o2 * 128 + b * T16 + J];
    __syncthreads();

    const int lane = t & 63, wv = t >> 6, colg = lane & 7, rowg = lane >> 3;
    const int r0 = wv * 32 + rowg * 4;
    float4 pr[4]; float srr[4];
#pragma unroll
    for (int rr = 0; rr < 4; rr++) { pr[rr] = p1s[r0 + rr]; srr[rr] = srs[r0 + rr]; }
    float racc[4] = {0.f, 0.f, 0.f, 0.f};
    float cacc[16];
#pragma unroll
    for (int j = 0; j < 16; j++) cacc[j] = 0.f;

#pragma unroll
    for (int j = 0; j < 16; j++) {
        const float4 q = p2s[colg + 8 * j];
        const float sc = scs[colg + 8 * j];
#pragma unroll
        for (int rr = 0; rr < 4; rr++) {
            const float4 p = pr[rr];
            float d = fmaf(p.x, q.x, fmaf(p.y, q.y, p.z * q.z));
            d = fminf(fmaxf(d, -CLIP), CLIP);
            const float u = fabsf(d);
            float pl = fmaf(u, K3, K2); pl = fmaf(u, pl, K1); pl = fmaf(u, pl, K0);
            const float rt = __builtin_amdgcn_sqrtf(1.f - u) * pl;
            const float ach = (d >= 0.f) ? rt : (pi_ieh - rt);
            racc[rr] = fmaf(q.w, __builtin_amdgcn_exp2f(srr[rr] - ach), racc[rr]);
            cacc[j]  = fmaf(p.w, __builtin_amdgcn_exp2f(sc - ach), cacc[j]);
        }
    }

#pragma unroll
    for (int j = 0; j < 16; j++) {
        float v = cacc[j];
        v += __shfl_xor(v, 8); v += __shfl_xor(v, 16); v += __shfl_xor(v, 32);
        cacc[j] = v;
    }
    if (rowg == 0) {
#pragma unroll
        for (int j = 0; j < 16; j++) colpart[wv][colg + 8 * j] = cacc[j];
    }
#pragma unroll
    for (int rr = 0; rr < 4; rr++) {
        float v = racc[rr];
        v += __shfl_xor(v, 1); v += __shfl_xor(v, 2); v += __shfl_xor(v, 4);
        racc[rr] = v;
    }
    if (colg == 0) {
        const size_t gr = (size_t)J * SARR + (size_t)b * NN + (size_t)I * TB + r0;
#pragma unroll
        for (int rr = 0; rr < 4; rr++)
            rowOut[gr + rr] = make_float2(G2 - srr[rr], racc[rr]);
    }
    __syncthreads();
    if (!diag && t < TB) {
        const float v = colpart[0][t] + colpart[1][t] + colpart[2][t] + colpart[3][t];
        const size_t gc = (size_t)I * SARR + (size_t)b * NN + (size_t)J * TB + t;
        colOut[gc] = make_float2(G1 - scs[t], v);
    }
}

// ---------------------------------------------------------------------------
// combine v3: TWO threads per row (8 partials each, shfl merge) for 2x
// occupancy; final call (do_out) fuses the output reduction via atomics.
// ---------------------------------------------------------------------------
__global__ __launch_bounds__(256)
void combine_kernel(const float2* __restrict__ pAX, const float2* __restrict__ pBY,
                    const float2* __restrict__ pAY, const float2* __restrict__ pBX,
                    float* __restrict__ ax, float* __restrict__ by,
                    float* __restrict__ ay, float* __restrict__ bx,
                    const float* __restrict__ gxw, const float* __restrict__ gyw,
                    float* __restrict__ Wall, float* __restrict__ Gall,
                    const float* __restrict__ alpha, const float* __restrict__ beta,
                    float* __restrict__ out,
                    float eps_ln2, float nieL2E, int do_avg, int do_out)
{
    const int tid = threadIdx.x;
    const int gid2 = blockIdx.x * 256 + tid;
    const int row = gid2 >> 1, half = gid2 & 1;
    const int o = row >> 14, i = row & (SARR - 1);
    const float2* P = (o == 0) ? pAX : (o == 1) ? pBY : (o == 2) ? pAY : pBX;
    float* pot = (o == 0) ? ax : (o == 1) ? by : (o == 2) ? ay : bx;
    float2 pr[8];
#pragma unroll
    for (int u = 0; u < 8; u++) pr[u] = P[(size_t)(half * 8 + u) * SARR + i];
    float M = -3.0e38f;
#pragma unroll
    for (int u = 0; u < 8; u++) M = fmaxf(M, (pr[u].y > 0.f) ? pr[u].x : -3.0e38f);
    float S = 0.f;
#pragma unroll
    for (int u = 0; u < 8; u++)
        S += pr[u].y * __builtin_amdgcn_exp2f(fminf(pr[u].x - M, 0.f));
    // merge the two halves of this row (lanes differ in bit 0)
    const float Mo = __shfl_xor(M, 1);
    const float So = __shfl_xor(S, 1);
    const float nm = fmaxf(M, Mo);
    S = S * __builtin_amdgcn_exp2f(M - nm) + So * __builtin_amdgcn_exp2f(Mo - nm);
    S = fmaxf(S, 1e-38f);
    float r = -eps_ln2 * (nm + __builtin_amdgcn_logf(S));
    if (do_avg) r = 0.5f * (r + pot[i]);
    if (half == 0) pot[i] = r;

    const int wv = tid >> 6;
    if (do_out) {
        // fused final reduction: out[b] += sum of sgn * w * r
        float c = 0.f;
        if (half == 0) {
            const float w = ((o == 0 || o == 3) ? alpha : beta)[i];
            const float sgn = (o == 0 || o == 1) ? -1.f : 1.f;
            c = sgn * w * r;
        }
        c += __shfl_xor(c, 1);  c += __shfl_xor(c, 2);  c += __shfl_xor(c, 4);
        c += __shfl_xor(c, 8);  c += __shfl_xor(c, 16); c += __shfl_xor(c, 32);
        __shared__ float bs[4];
        if ((tid & 63) == 0) bs[wv] = c;
        __syncthreads();
        if (tid == 0) atomicAdd(&out[i >> 11], bs[0] + bs[1] + bs[2] + bs[3]);
        return;
    }

    const float g = ((o == 0 || o == 3) ? gxw[i] : gyw[i]) + r * nieL2E;
    // block covers exactly 128 rows -> one Gall entry; max over 256 threads
    float m = g;
    m = fmaxf(m, __shfl_xor(m, 1));  m = fmaxf(m, __shfl_xor(m, 2));
    m = fmaxf(m, __shfl_xor(m, 4));  m = fmaxf(m, __shfl_xor(m, 8));
    m = fmaxf(m, __shfl_xor(m, 16)); m = fmaxf(m, __shfl_xor(m, 32));
    __shared__ float wmax[4];
    if ((tid & 63) == 0) wmax[wv] = m;
    __syncthreads();
    const float G = fmaxf(fmaxf(wmax[0], wmax[1]), fmaxf(wmax[2], wmax[3]));
    if (half == 0) Wall[row] = __builtin_amdgcn_exp2f(g - G);
    if (tid == 0) Gall[blockIdx.x] = G;
}

// ---------------------------------------------------------------------------
extern "C" void kernel_launch(void* const* d_in, const int* in_sizes, int n_in,
                              void* d_out, int out_size, void* d_ws, size_t ws_size,
                              hipStream_t stream)
{
    const float* alpha = (const float*)d_in[0];
    const float* x     = (const float*)d_in[1];
    const float* beta  = (const float*)d_in[2];
    const float* y     = (const float*)d_in[3];
    float* out = (float*)d_out;
    float* ws  = (float*)d_ws;

    const size_t S = SARR;
    float* gxw  = ws;
    float* gyw  = ws + S;
    float* ax   = ws + 2 * S;
    float* by   = ws + 3 * S;
    float* ay   = ws + 4 * S;
    float* bx   = ws + 5 * S;
    float* Wall = ws + 6 * S;              // 4*S
    float* Gall = ws + 10 * S;             // 512
    float* Rxx  = ws + 10 * S + 512;       // 16*S each (theta of max-dot)
    float* Ryy  = Rxx + 16 * S;
    float* Rxy  = Ryy + 16 * S;
    float* Cxy  = Rxy + 16 * S;
    float* pb   = Cxy + 16 * S;
    const size_t PSZ = (size_t)SARR * T16;
    float2* pAX = (float2*)pb;
    float2* pBY = pAX + PSZ;
    float2* pAY = pBY + PSZ;
    float2* pBX = pAY + PSZ;

    // theta cache lives after the partial buffers (16-B aligned by construction)
    float* thetaF = pb + (size_t)8 * PSZ;
    unsigned short* Theta = (unsigned short*)thetaF;
    const size_t used_bytes  = (size_t)((char*)thetaF - (char*)ws);
    const size_t theta_bytes = (size_t)BB * NT * 16384 * sizeof(unsigned short); // ~138 MB
    const int useTheta = (ws_size >= used_bytes + theta_bytes) ? 1 : 0;

    const float EPS[8] = {4.0f, 4.0f, 1.0f, 0.25f, 0.0625f, 0.015625f, 0.00390625f, 0.0025f};

    pack_kernel<<<(4 * SARR) / 256, 256, 0, stream>>>(alpha, beta, gxw, gyw, Wall, Gall, out);
    // maxes: geometry + theta + FUSED INIT step (eps = EPS[0], shift-free)
    const float negK = -0.5f * (1.f / EPS[0]) * L2E;
    maxes_kernel<<<dim3(NT, BB), 256, 0, stream>>>(x, y, Rxx, Ryy, Rxy, Cxy, Theta,
                                                   Wall, Gall, pAX, pBY, pAY, pBX,
                                                   negK, useTheta);

    TileArgsT TT;
    TT.Theta = Theta; TT.Wall = Wall; TT.Gall = Gall;
    TT.Rxx = Rxx; TT.Ryy = Ryy; TT.Rxy = Rxy; TT.Cxy = Cxy;
    TT.pAX = pAX; TT.pBY = pBY; TT.pAY = pAY; TT.pBX = pBX;

    TileArgs TA;
    TA.x = x; TA.y = y; TA.Wall = Wall; TA.Gall = Gall;
    TA.Rxx = Rxx; TA.Ryy = Ryy; TA.Rxy = Rxy; TA.Cxy = Cxy;
    TA.pAX = pAX; TA.pBY = pBY; TA.pAY = pAY; TA.pBX = pBX;

    auto step = [&](float e, float next_e, int avg, int run_tile, int do_out) {
        const float ieh = 0.5f * (1.f / e) * L2E;
        if (run_tile) {
            if (useTheta)
                tile_theta_kernel<<<dim3(NT, BB), 256, 0, stream>>>(TT, ieh, ieh * THSCI);
            else
                tile_kernel<<<dim3(NT, BB), 256, 0, stream>>>(TA, ieh, PI_F * ieh);
        }
        combine_kernel<<<(8 * SARR) / 256, 256, 0, stream>>>(
            pAX, pBY, pAY, pBX, ax, by, ay, bx, gxw, gyw, Wall, Gall,
            alpha, beta, out,
            e * LN2, (1.f / next_e) * L2E, avg, do_out);
    };

    // init: tile pass fused into maxes when theta path active
    step(EPS[0], EPS[0], 0, useTheta ? 0 : 1, 0);
    for (int k = 0; k < 8; k++) step(EPS[k], (k < 7) ? EPS[k + 1] : EPS[7], 1, 1, 0);
    step(EPS[7], EPS[7], 0, 1, 1);   // final extrapolation + fused output reduce
}